// Round 12
// baseline (58.746 us; speedup 1.0000x reference)
//
#include <hip/hip_runtime.h>
#include <hip/hip_bf16.h>
#include <math.h>

#define N_TOK 4096
#define M_TOK 1024
#define DMODEL 512
#define NHEAD 8
#define DHEAD 64

typedef __attribute__((ext_vector_type(8))) short short8;
typedef __attribute__((ext_vector_type(4))) float f32x4;
typedef __attribute__((ext_vector_type(4))) float float4v;

static __device__ __forceinline__ short f2bf(float f) {
    union { float f; unsigned u; } v; v.f = f;
    unsigned r = v.u + 0x7fffu + ((v.u >> 16) & 1u);
    return (short)(r >> 16);
}

// ---------------------------------------------------------------------------
// Pack v2 (r11-proven). Blocks [0,192): wq/wk/wv head-tile transposes via
// LDS. Blocks [192,256): wo. Blocks [256+): xv/xt bf16 conversion.
// ---------------------------------------------------------------------------
__global__ __launch_bounds__(256) void pack_kernel(
        const float* __restrict__ xv, const float* __restrict__ xt,
        const float* __restrict__ wq, const float* __restrict__ wk,
        const float* __restrict__ wv, const float* __restrict__ wo,
        short* __restrict__ xvb, short* __restrict__ xtb,
        short* __restrict__ wqb, short* __restrict__ wkb,
        short* __restrict__ wvb, short* __restrict__ wob) {
    int bid = blockIdx.x;
    int t = threadIdx.x;
    if (bid < 256) {
        __shared__ float lds[64][65];
        const float* src;
        short* dst;
        int srstride;
        int dr0, dc0;
        if (bid < 192) {
            int mat = bid >> 6;
            int hb = bid & 63;
            int h = hb >> 3, dt = hb & 7;
            const float* W = (mat == 0) ? wq : (mat == 1) ? wk : wv;
            src = W + (size_t)h * (DMODEL * DHEAD) + (size_t)(dt * 64) * DHEAD;
            srstride = DHEAD;
            dst = (mat == 0) ? wqb : (mat == 1) ? wkb : wvb;
            dr0 = h * 64;
            dc0 = dt * 64;
        } else {
            int b = bid - 192;
            int rt = b >> 3, ct = b & 7;
            src = wo + (size_t)(rt * 64) * DMODEL + ct * 64;
            srstride = DMODEL;
            dst = wob;
            dr0 = ct * 64;
            dc0 = rt * 64;
        }
        {
            int r = t >> 2, c0 = (t & 3) * 16;
            const float* s = src + (size_t)r * srstride + c0;
            #pragma unroll
            for (int j = 0; j < 4; j++) {
                float4v v = *(const float4v*)(s + j * 4);
                lds[r][c0 + j * 4 + 0] = v[0];
                lds[r][c0 + j * 4 + 1] = v[1];
                lds[r][c0 + j * 4 + 2] = v[2];
                lds[r][c0 + j * 4 + 3] = v[3];
            }
        }
        __syncthreads();
        {
            int outr = t >> 2, c0 = (t & 3) * 16;
            short8 o0, o1;
            #pragma unroll
            for (int j = 0; j < 8; j++) {
                o0[j] = f2bf(lds[c0 + j][outr]);
                o1[j] = f2bf(lds[c0 + 8 + j][outr]);
            }
            short* d = dst + (size_t)(dr0 + outr) * DMODEL + dc0 + c0;
            *(short8*)d = o0;
            *(short8*)(d + 8) = o1;
        }
        return;
    }
    int idx = (bid - 256) * 256 + t;
    int stride = (gridDim.x - 256) * 256;
    const int CXV = N_TOK * DMODEL / 8;
    const int CXT = M_TOK * DMODEL / 8;
    for (int c = idx; c < CXV; c += stride) {
        float4v f0 = *(const float4v*)&xv[c * 8];
        float4v f1 = *(const float4v*)&xv[c * 8 + 4];
        short8 o;
        #pragma unroll
        for (int j = 0; j < 4; j++) { o[j] = f2bf(f0[j]); o[j + 4] = f2bf(f1[j]); }
        *(short8*)&xvb[c * 8] = o;
    }
    for (int c = idx; c < CXT; c += stride) {
        float4v f0 = *(const float4v*)&xt[c * 8];
        float4v f1 = *(const float4v*)&xt[c * 8 + 4];
        short8 o;
        #pragma unroll
        for (int j = 0; j < 4; j++) { o[j] = f2bf(f0[j]); o[j + 4] = f2bf(f1[j]); }
        *(short8*)&xtb[c * 8] = o;
    }
}

// ---------------------------------------------------------------------------
// GEMM body (r5/r8-proven): 64x64, BK=64, padded LDS, reg-staging with
// next-step loads issued right after the barrier. Wave (wr,wc) = 32x32 quad.
// ---------------------------------------------------------------------------
template<typename EPI>
static __device__ __forceinline__ void gemm_body(const short* __restrict__ A,
                                                 const short* __restrict__ BT,
                                                 int m0, int n0, EPI epi) {
    __shared__ __align__(16) short As[64][72];
    __shared__ __align__(16) short Bs[64][72];
    int t = threadIdx.x;
    int lane = t & 63, w = t >> 6;
    int wr = w >> 1, wc = w & 1;
    int l15 = lane & 15, g = lane >> 4;

    int row = t >> 2, c0 = (t & 3) * 16;
    const short* gA = A + (size_t)(m0 + row) * DMODEL + c0;
    const short* gB = BT + (size_t)(n0 + row) * DMODEL + c0;

    short8 ra0 = *(const short8*)gA;
    short8 ra1 = *(const short8*)(gA + 8);
    short8 rb0 = *(const short8*)gB;
    short8 rb1 = *(const short8*)(gB + 8);

    f32x4 acc[2][2] = {};
    #pragma unroll
    for (int step = 0; step < DMODEL / 64; ++step) {
        *(short8*)&As[row][c0]     = ra0;
        *(short8*)&As[row][c0 + 8] = ra1;
        *(short8*)&Bs[row][c0]     = rb0;
        *(short8*)&Bs[row][c0 + 8] = rb1;
        __syncthreads();
        if (step < DMODEL / 64 - 1) {
            gA += 64; gB += 64;
            ra0 = *(const short8*)gA;
            ra1 = *(const short8*)(gA + 8);
            rb0 = *(const short8*)gB;
            rb1 = *(const short8*)(gB + 8);
        }
        #pragma unroll
        for (int ks = 0; ks < 2; ks++) {
            short8 a[2], b[2];
            #pragma unroll
            for (int fr = 0; fr < 2; fr++) a[fr] = *(short8*)&As[wr * 32 + fr * 16 + l15][ks * 32 + g * 8];
            #pragma unroll
            for (int fc = 0; fc < 2; fc++) b[fc] = *(short8*)&Bs[wc * 32 + fc * 16 + l15][ks * 32 + g * 8];
            #pragma unroll
            for (int fr = 0; fr < 2; fr++)
                #pragma unroll
                for (int fc = 0; fc < 2; fc++)
                    acc[fr][fc] = __builtin_amdgcn_mfma_f32_16x16x32_bf16(a[fr], b[fc], acc[fr][fc], 0, 0, 0);
        }
        __syncthreads();
    }
    #pragma unroll
    for (int fr = 0; fr < 2; fr++)
        #pragma unroll
        for (int fc = 0; fc < 2; fc++)
            #pragma unroll
            for (int r = 0; r < 4; r++) {
                int orow = m0 + wr * 32 + fr * 16 + g * 4 + r;
                int ocol = n0 + wc * 32 + fc * 16 + l15;
                epi(orow, ocol, acc[fr][fc][r]);
            }
}

// ---------------------------------------------------------------------------
// Q, K, V projections in ONE launch. grid (96, 8).
// ---------------------------------------------------------------------------
__global__ __launch_bounds__(256) void gemmQKV(const short* __restrict__ xvb,
                                               const short* __restrict__ xtb,
                                               const short* __restrict__ wqb,
                                               const short* __restrict__ wkb,
                                               const short* __restrict__ wvb,
                                               short* __restrict__ qb,
                                               short* __restrict__ kbm,
                                               short* __restrict__ vbt) {
    int bx = blockIdx.x;
    int n0 = blockIdx.y * 64;
    if (bx < 64) {
        short* C = qb;
        gemm_body(xvb, wqb, bx * 64, n0,
                  [&](int row, int col, float v) { C[(size_t)row * DMODEL + col] = f2bf(v); });
    } else if (bx < 80) {
        short* C = kbm;
        gemm_body(xtb, wkb, (bx - 64) * 64, n0,
                  [&](int row, int col, float v) { C[(size_t)row * DMODEL + col] = f2bf(v); });
    } else {
        short* C = vbt;
        gemm_body(xtb, wvb, (bx - 80) * 64, n0,
                  [&](int row, int col, float v) { C[(size_t)col * M_TOK + row] = f2bf(v); });
    }
}

// ---------------------------------------------------------------------------
// Final GEMM: out = Y * Wout(^T stored) + PE (inline sincos, LDS ifreq).
// ---------------------------------------------------------------------------
__global__ __launch_bounds__(256) void gemmOut(const short* __restrict__ A,
                                               const short* __restrict__ BT,
                                               float* __restrict__ Cout) {
    __shared__ float ifreq[256];
    ifreq[threadIdx.x] = __expf(-(float)threadIdx.x * (9.210340371976184f / 512.0f));
    __syncthreads();
    gemm_body(A, BT, blockIdx.x * 64, blockIdx.y * 64,
              [&](int row, int col, float v) {
                  float x = (float)row * ifreq[col >> 1];
                  float s, c;
                  __sincosf(x, &s, &c);
                  Cout[(size_t)row * DMODEL + col] = v + ((col & 1) ? c : s);
              });
}

// ---------------------------------------------------------------------------
// Attention v6: reg-staged K/V (the r8 GEMM pattern) — per-thread short8
// global loads -> regs -> padded LDS; next-tile loads issued right after the
// first barrier so HBM/L2 latency hides under QK/exp/PV. Single buffer,
// 2 barriers/iter. Block = 64 q x 1 head, wave = 16 q x all keys, no merge.
// ---------------------------------------------------------------------------
__global__ __launch_bounds__(256) void attn_kernel(const short* __restrict__ Qb,
                                                   const short* __restrict__ Kb,
                                                   const short* __restrict__ VbT,
                                                   short* __restrict__ Yb) {
    __shared__ __align__(16) short Ks[64][72];   // keys x d   (9 KB)
    __shared__ __align__(16) short Vt[64][72];   // d x keys   (9 KB)
    __shared__ __align__(16) short Ps[4][16][72];

    int bid = blockIdx.x;
    int h = bid & 7;
    int n0 = (bid >> 3) * 64;
    int t = threadIdx.x;
    int lane = t & 63, w = t >> 6;
    int l15 = lane & 15, g = lane >> 4;

    // staging: thread -> (row, 16-col chunk)
    int row = t >> 2, c0 = (t & 3) * 16;
    const short* gK = Kb + (size_t)row * DMODEL + h * DHEAD + c0;      // key=row
    const short* gV = VbT + (size_t)(h * DHEAD + row) * M_TOK + c0;    // d=row, key=c0

    short8 k0 = *(const short8*)gK;
    short8 k1 = *(const short8*)(gK + 8);
    short8 v0 = *(const short8*)gV;
    short8 v1 = *(const short8*)(gV + 8);

    const short* qrow = Qb + (size_t)(n0 + w * 16 + l15) * DMODEL + h * DHEAD;
    short8 qa0 = *(const short8*)(qrow + g * 8);
    short8 qa1 = *(const short8*)(qrow + 32 + g * 8);

    f32x4 acc[4] = {};
    f32x4 rsum = {};

    for (int it = 0; it < 16; ++it) {
        *(short8*)&Ks[row][c0]     = k0;
        *(short8*)&Ks[row][c0 + 8] = k1;
        *(short8*)&Vt[row][c0]     = v0;
        *(short8*)&Vt[row][c0 + 8] = v1;
        __syncthreads();
        if (it < 15) {                       // issue next-tile loads early
            gK += (size_t)64 * DMODEL;
            gV += 64;
            k0 = *(const short8*)gK;
            k1 = *(const short8*)(gK + 8);
            v0 = *(const short8*)gV;
            v1 = *(const short8*)(gV + 8);
        }
        // QK^T over 64 keys
        #pragma unroll
        for (int kt = 0; kt < 4; kt++) {
            short8 kf0 = *(short8*)&Ks[kt * 16 + l15][g * 8];
            short8 kf1 = *(short8*)&Ks[kt * 16 + l15][32 + g * 8];
            f32x4 e = {};
            e = __builtin_amdgcn_mfma_f32_16x16x32_bf16(qa0, kf0, e, 0, 0, 0);
            e = __builtin_amdgcn_mfma_f32_16x16x32_bf16(qa1, kf1, e, 0, 0, 0);
            #pragma unroll
            for (int r = 0; r < 4; r++) {
                float p = exp2f(e[r] * 1.44269504f);
                rsum[r] += p;
                Ps[w][g * 4 + r][kt * 16 + l15] = f2bf(p);
            }
        }
        // PV over 64 keys
        #pragma unroll
        for (int kb2 = 0; kb2 < 2; kb2++) {
            short8 pa = *(short8*)&Ps[w][l15][kb2 * 32 + g * 8];
            #pragma unroll
            for (int nt = 0; nt < 4; nt++) {
                short8 vf = *(short8*)&Vt[nt * 16 + l15][kb2 * 32 + g * 8];
                acc[nt] = __builtin_amdgcn_mfma_f32_16x16x32_bf16(pa, vf, acc[nt], 0, 0, 0);
            }
        }
        __syncthreads();
    }

    #pragma unroll
    for (int r = 0; r < 4; r++) {
        float s = rsum[r];
        s += __shfl_xor(s, 1);
        s += __shfl_xor(s, 2);
        s += __shfl_xor(s, 4);
        s += __shfl_xor(s, 8);
        rsum[r] = s;
    }

    #pragma unroll
    for (int nt = 0; nt < 4; nt++)
        #pragma unroll
        for (int r = 0; r < 4; r++) {
            float y = acc[nt][r] / rsum[r];
            Yb[(size_t)(n0 + w * 16 + g * 4 + r) * DMODEL + h * DHEAD + nt * 16 + l15] = f2bf(y);
        }
}

// ---------------------------------------------------------------------------
extern "C" void kernel_launch(void* const* d_in, const int* in_sizes, int n_in,
                              void* d_out, int out_size, void* d_ws, size_t ws_size,
                              hipStream_t stream) {
    const float* xv = (const float*)d_in[0];
    const float* xt = (const float*)d_in[1];
    const float* wq = (const float*)d_in[2];
    const float* wk = (const float*)d_in[3];
    const float* wv = (const float*)d_in[4];
    const float* wo = (const float*)d_in[5];

    short* xvb = (short*)d_ws;              // 4096*512
    short* xtb = xvb + N_TOK * DMODEL;      // 1024*512
    short* wqb = xtb + M_TOK * DMODEL;      // 512*512 (B^T)
    short* wkb = wqb + DMODEL * DMODEL;
    short* wvb = wkb + DMODEL * DMODEL;
    short* wob = wvb + DMODEL * DMODEL;
    short* qb  = wob + DMODEL * DMODEL;     // 4096*512
    short* kbm = qb  + N_TOK * DMODEL;      // 1024*512
    short* vbt = kbm + M_TOK * DMODEL;      // 512*1024 (V^T)
    short* yb  = vbt + M_TOK * DMODEL;      // 4096*512

    pack_kernel<<<1280, 256, 0, stream>>>(xv, xt, wq, wk, wv, wo,
                                          xvb, xtb, wqb, wkb, wvb, wob);
    gemmQKV<<<dim3(96, 8), 256, 0, stream>>>(xvb, xtb, wqb, wkb, wvb, qb, kbm, vbt);
    attn_kernel<<<512, 256, 0, stream>>>(qb, kbm, vbt, yb);
    gemmOut<<<dim3(64, 8), 256, 0, stream>>>(yb, wob, (float*)d_out);
}

// Round 13
// 53.747 us; speedup vs baseline: 1.0930x; 1.0930x over previous
//
#include <hip/hip_runtime.h>
#include <hip/hip_bf16.h>
#include <math.h>

#define N_TOK 4096
#define M_TOK 1024
#define DMODEL 512
#define NHEAD 8
#define DHEAD 64

typedef __attribute__((ext_vector_type(8))) short short8;
typedef __attribute__((ext_vector_type(4))) float f32x4;
typedef __attribute__((ext_vector_type(4))) float float4v;

static __device__ __forceinline__ short f2bf(float f) {
    union { float f; unsigned u; } v; v.f = f;
    unsigned r = v.u + 0x7fffu + ((v.u >> 16) & 1u);
    return (short)(r >> 16);
}

// ---------------------------------------------------------------------------
// Pack v2 (r11-proven). Blocks [0,192): wq/wk/wv head-tile transposes via
// LDS. Blocks [192,256): wo. Blocks [256+): xv/xt bf16 conversion.
// ---------------------------------------------------------------------------
__global__ __launch_bounds__(256) void pack_kernel(
        const float* __restrict__ xv, const float* __restrict__ xt,
        const float* __restrict__ wq, const float* __restrict__ wk,
        const float* __restrict__ wv, const float* __restrict__ wo,
        short* __restrict__ xvb, short* __restrict__ xtb,
        short* __restrict__ wqb, short* __restrict__ wkb,
        short* __restrict__ wvb, short* __restrict__ wob) {
    int bid = blockIdx.x;
    int t = threadIdx.x;
    if (bid < 256) {
        __shared__ float lds[64][65];
        const float* src;
        short* dst;
        int srstride;
        int dr0, dc0;
        if (bid < 192) {
            int mat = bid >> 6;
            int hb = bid & 63;
            int h = hb >> 3, dt = hb & 7;
            const float* W = (mat == 0) ? wq : (mat == 1) ? wk : wv;
            src = W + (size_t)h * (DMODEL * DHEAD) + (size_t)(dt * 64) * DHEAD;
            srstride = DHEAD;
            dst = (mat == 0) ? wqb : (mat == 1) ? wkb : wvb;
            dr0 = h * 64;
            dc0 = dt * 64;
        } else {
            int b = bid - 192;
            int rt = b >> 3, ct = b & 7;
            src = wo + (size_t)(rt * 64) * DMODEL + ct * 64;
            srstride = DMODEL;
            dst = wob;
            dr0 = ct * 64;
            dc0 = rt * 64;
        }
        {
            int r = t >> 2, c0 = (t & 3) * 16;
            const float* s = src + (size_t)r * srstride + c0;
            #pragma unroll
            for (int j = 0; j < 4; j++) {
                float4v v = *(const float4v*)(s + j * 4);
                lds[r][c0 + j * 4 + 0] = v[0];
                lds[r][c0 + j * 4 + 1] = v[1];
                lds[r][c0 + j * 4 + 2] = v[2];
                lds[r][c0 + j * 4 + 3] = v[3];
            }
        }
        __syncthreads();
        {
            int outr = t >> 2, c0 = (t & 3) * 16;
            short8 o0, o1;
            #pragma unroll
            for (int j = 0; j < 8; j++) {
                o0[j] = f2bf(lds[c0 + j][outr]);
                o1[j] = f2bf(lds[c0 + 8 + j][outr]);
            }
            short* d = dst + (size_t)(dr0 + outr) * DMODEL + dc0 + c0;
            *(short8*)d = o0;
            *(short8*)(d + 8) = o1;
        }
        return;
    }
    int idx = (bid - 256) * 256 + t;
    int stride = (gridDim.x - 256) * 256;
    const int CXV = N_TOK * DMODEL / 8;
    const int CXT = M_TOK * DMODEL / 8;
    for (int c = idx; c < CXV; c += stride) {
        float4v f0 = *(const float4v*)&xv[c * 8];
        float4v f1 = *(const float4v*)&xv[c * 8 + 4];
        short8 o;
        #pragma unroll
        for (int j = 0; j < 4; j++) { o[j] = f2bf(f0[j]); o[j + 4] = f2bf(f1[j]); }
        *(short8*)&xvb[c * 8] = o;
    }
    for (int c = idx; c < CXT; c += stride) {
        float4v f0 = *(const float4v*)&xt[c * 8];
        float4v f1 = *(const float4v*)&xt[c * 8 + 4];
        short8 o;
        #pragma unroll
        for (int j = 0; j < 4; j++) { o[j] = f2bf(f0[j]); o[j + 4] = f2bf(f1[j]); }
        *(short8*)&xtb[c * 8] = o;
    }
}

// ---------------------------------------------------------------------------
// GEMM body (r5/r8-proven): 64x64, BK=64, padded LDS, reg-staging with
// next-step loads issued right after the barrier. Wave (wr,wc) = 32x32 quad.
// ---------------------------------------------------------------------------
template<typename EPI>
static __device__ __forceinline__ void gemm_body(const short* __restrict__ A,
                                                 const short* __restrict__ BT,
                                                 int m0, int n0, EPI epi) {
    __shared__ __align__(16) short As[64][72];
    __shared__ __align__(16) short Bs[64][72];
    int t = threadIdx.x;
    int lane = t & 63, w = t >> 6;
    int wr = w >> 1, wc = w & 1;
    int l15 = lane & 15, g = lane >> 4;

    int row = t >> 2, c0 = (t & 3) * 16;
    const short* gA = A + (size_t)(m0 + row) * DMODEL + c0;
    const short* gB = BT + (size_t)(n0 + row) * DMODEL + c0;

    short8 ra0 = *(const short8*)gA;
    short8 ra1 = *(const short8*)(gA + 8);
    short8 rb0 = *(const short8*)gB;
    short8 rb1 = *(const short8*)(gB + 8);

    f32x4 acc[2][2] = {};
    #pragma unroll
    for (int step = 0; step < DMODEL / 64; ++step) {
        *(short8*)&As[row][c0]     = ra0;
        *(short8*)&As[row][c0 + 8] = ra1;
        *(short8*)&Bs[row][c0]     = rb0;
        *(short8*)&Bs[row][c0 + 8] = rb1;
        __syncthreads();
        if (step < DMODEL / 64 - 1) {
            gA += 64; gB += 64;
            ra0 = *(const short8*)gA;
            ra1 = *(const short8*)(gA + 8);
            rb0 = *(const short8*)gB;
            rb1 = *(const short8*)(gB + 8);
        }
        #pragma unroll
        for (int ks = 0; ks < 2; ks++) {
            short8 a[2], b[2];
            #pragma unroll
            for (int fr = 0; fr < 2; fr++) a[fr] = *(short8*)&As[wr * 32 + fr * 16 + l15][ks * 32 + g * 8];
            #pragma unroll
            for (int fc = 0; fc < 2; fc++) b[fc] = *(short8*)&Bs[wc * 32 + fc * 16 + l15][ks * 32 + g * 8];
            #pragma unroll
            for (int fr = 0; fr < 2; fr++)
                #pragma unroll
                for (int fc = 0; fc < 2; fc++)
                    acc[fr][fc] = __builtin_amdgcn_mfma_f32_16x16x32_bf16(a[fr], b[fc], acc[fr][fc], 0, 0, 0);
        }
        __syncthreads();
    }
    #pragma unroll
    for (int fr = 0; fr < 2; fr++)
        #pragma unroll
        for (int fc = 0; fc < 2; fc++)
            #pragma unroll
            for (int r = 0; r < 4; r++) {
                int orow = m0 + wr * 32 + fr * 16 + g * 4 + r;
                int ocol = n0 + wc * 32 + fc * 16 + l15;
                epi(orow, ocol, acc[fr][fc][r]);
            }
}

// ---------------------------------------------------------------------------
// Q, K, V projections in ONE launch. grid (96, 8).
// ---------------------------------------------------------------------------
__global__ __launch_bounds__(256) void gemmQKV(const short* __restrict__ xvb,
                                               const short* __restrict__ xtb,
                                               const short* __restrict__ wqb,
                                               const short* __restrict__ wkb,
                                               const short* __restrict__ wvb,
                                               short* __restrict__ qb,
                                               short* __restrict__ kbm,
                                               short* __restrict__ vbt) {
    int bx = blockIdx.x;
    int n0 = blockIdx.y * 64;
    if (bx < 64) {
        short* C = qb;
        gemm_body(xvb, wqb, bx * 64, n0,
                  [&](int row, int col, float v) { C[(size_t)row * DMODEL + col] = f2bf(v); });
    } else if (bx < 80) {
        short* C = kbm;
        gemm_body(xtb, wkb, (bx - 64) * 64, n0,
                  [&](int row, int col, float v) { C[(size_t)row * DMODEL + col] = f2bf(v); });
    } else {
        short* C = vbt;
        gemm_body(xtb, wvb, (bx - 80) * 64, n0,
                  [&](int row, int col, float v) { C[(size_t)col * M_TOK + row] = f2bf(v); });
    }
}

// ---------------------------------------------------------------------------
// Final GEMM: out = Y * Wout(^T stored) + PE (inline sincos, LDS ifreq).
// ---------------------------------------------------------------------------
__global__ __launch_bounds__(256) void gemmOut(const short* __restrict__ A,
                                               const short* __restrict__ BT,
                                               float* __restrict__ Cout) {
    __shared__ float ifreq[256];
    ifreq[threadIdx.x] = __expf(-(float)threadIdx.x * (9.210340371976184f / 512.0f));
    __syncthreads();
    gemm_body(A, BT, blockIdx.x * 64, blockIdx.y * 64,
              [&](int row, int col, float v) {
                  float x = (float)row * ifreq[col >> 1];
                  float s, c;
                  __sincosf(x, &s, &c);
                  Cout[(size_t)row * DMODEL + col] = v + ((col & 1) ? c : s);
              });
}

// ---------------------------------------------------------------------------
// Attention v7: 512 threads = 8 waves = 4 q-subtiles x 2 KEY-HALVES.
// Block = 64 q x 1 head (K/V reuse per block unchanged -> FETCH unchanged),
// but 16 waves/CU instead of 8 -> 2x latency hiding on the serial
// ds_read->MFMA->exp->P->MFMA chain. Each wave: 16 q x 512 keys, 8 iters.
// Single-pass exp2 softmax => 2-way merge is a plain sum via conflict-free
// [qg][nt][lane] f32x4 LDS overlay (union, barrier-protected).
// ---------------------------------------------------------------------------
struct AttnS {
    short Ks[2][64][72];   // [key-half][key][d]
    short Vt[2][64][72];   // [key-half][d][key]
    short Ps[8][16][72];   // per-wave P tile
};
struct MergeS {
    f32x4 macc[4][4][64];  // [qg][nt][lane]
    f32x4 mrs[4][64];      // [qg][lane]
};
union AttnU { AttnS a; MergeS m; };

__global__ __launch_bounds__(512) void attn_kernel(const short* __restrict__ Qb,
                                                   const short* __restrict__ Kb,
                                                   const short* __restrict__ VbT,
                                                   short* __restrict__ Yb) {
    __shared__ __align__(16) AttnU u;

    int bid = blockIdx.x;
    int h = bid & 7;
    int n0 = (bid >> 3) * 64;
    int t = threadIdx.x;
    int lane = t & 63, w = t >> 6;
    int qg = w & 3, kh = w >> 2;
    int l15 = lane & 15, g = lane >> 4;

    // staging: threads [0,256) stage key-half 0, [256,512) half 1
    int sh = t >> 8;
    int tt = t & 255;
    int row = tt >> 2, c0 = (tt & 3) * 16;
    const short* gK = Kb + (size_t)(sh * 512 + row) * DMODEL + h * DHEAD + c0;
    const short* gV = VbT + (size_t)(h * DHEAD + row) * M_TOK + sh * 512 + c0;

    short8 k0 = *(const short8*)gK;
    short8 k1 = *(const short8*)(gK + 8);
    short8 v0 = *(const short8*)gV;
    short8 v1 = *(const short8*)(gV + 8);

    const short* qrow = Qb + (size_t)(n0 + qg * 16 + l15) * DMODEL + h * DHEAD;
    short8 qa0 = *(const short8*)(qrow + g * 8);
    short8 qa1 = *(const short8*)(qrow + 32 + g * 8);

    f32x4 acc[4] = {};
    f32x4 rsum = {};

    for (int it = 0; it < 8; ++it) {
        *(short8*)&u.a.Ks[sh][row][c0]     = k0;
        *(short8*)&u.a.Ks[sh][row][c0 + 8] = k1;
        *(short8*)&u.a.Vt[sh][row][c0]     = v0;
        *(short8*)&u.a.Vt[sh][row][c0 + 8] = v1;
        __syncthreads();
        if (it < 7) {                        // issue next-tile loads early
            gK += (size_t)64 * DMODEL;
            gV += 64;
            k0 = *(const short8*)gK;
            k1 = *(const short8*)(gK + 8);
            v0 = *(const short8*)gV;
            v1 = *(const short8*)(gV + 8);
        }
        // QK^T over this wave's 64 keys
        #pragma unroll
        for (int kt = 0; kt < 4; kt++) {
            short8 kf0 = *(short8*)&u.a.Ks[kh][kt * 16 + l15][g * 8];
            short8 kf1 = *(short8*)&u.a.Ks[kh][kt * 16 + l15][32 + g * 8];
            f32x4 e = {};
            e = __builtin_amdgcn_mfma_f32_16x16x32_bf16(qa0, kf0, e, 0, 0, 0);
            e = __builtin_amdgcn_mfma_f32_16x16x32_bf16(qa1, kf1, e, 0, 0, 0);
            #pragma unroll
            for (int r = 0; r < 4; r++) {
                float p = exp2f(e[r] * 1.44269504f);
                rsum[r] += p;
                u.a.Ps[w][g * 4 + r][kt * 16 + l15] = f2bf(p);
            }
        }
        // PV over this wave's 64 keys
        #pragma unroll
        for (int kb2 = 0; kb2 < 2; kb2++) {
            short8 pa = *(short8*)&u.a.Ps[w][l15][kb2 * 32 + g * 8];
            #pragma unroll
            for (int nt = 0; nt < 4; nt++) {
                short8 vf = *(short8*)&u.a.Vt[kh][nt * 16 + l15][kb2 * 32 + g * 8];
                acc[nt] = __builtin_amdgcn_mfma_f32_16x16x32_bf16(pa, vf, acc[nt], 0, 0, 0);
            }
        }
        __syncthreads();
    }

    // merge the two key-halves (plain sum; overlay reuses the staging LDS)
    if (kh == 1) {
        #pragma unroll
        for (int nt = 0; nt < 4; nt++) u.m.macc[qg][nt][lane] = acc[nt];
        u.m.mrs[qg][lane] = rsum;
    }
    __syncthreads();
    if (kh == 0) {
        #pragma unroll
        for (int nt = 0; nt < 4; nt++) acc[nt] += u.m.macc[qg][nt][lane];
        rsum += u.m.mrs[qg][lane];
        #pragma unroll
        for (int r = 0; r < 4; r++) {
            float s = rsum[r];
            s += __shfl_xor(s, 1);
            s += __shfl_xor(s, 2);
            s += __shfl_xor(s, 4);
            s += __shfl_xor(s, 8);
            rsum[r] = s;
        }
        #pragma unroll
        for (int nt = 0; nt < 4; nt++)
            #pragma unroll
            for (int r = 0; r < 4; r++) {
                float y = acc[nt][r] / rsum[r];
                Yb[(size_t)(n0 + qg * 16 + g * 4 + r) * DMODEL + h * DHEAD + nt * 16 + l15] = f2bf(y);
            }
    }
}

// ---------------------------------------------------------------------------
extern "C" void kernel_launch(void* const* d_in, const int* in_sizes, int n_in,
                              void* d_out, int out_size, void* d_ws, size_t ws_size,
                              hipStream_t stream) {
    const float* xv = (const float*)d_in[0];
    const float* xt = (const float*)d_in[1];
    const float* wq = (const float*)d_in[2];
    const float* wk = (const float*)d_in[3];
    const float* wv = (const float*)d_in[4];
    const float* wo = (const float*)d_in[5];

    short* xvb = (short*)d_ws;              // 4096*512
    short* xtb = xvb + N_TOK * DMODEL;      // 1024*512
    short* wqb = xtb + M_TOK * DMODEL;      // 512*512 (B^T)
    short* wkb = wqb + DMODEL * DMODEL;
    short* wvb = wkb + DMODEL * DMODEL;
    short* wob = wvb + DMODEL * DMODEL;
    short* qb  = wob + DMODEL * DMODEL;     // 4096*512
    short* kbm = qb  + N_TOK * DMODEL;      // 1024*512
    short* vbt = kbm + M_TOK * DMODEL;      // 512*1024 (V^T)
    short* yb  = vbt + M_TOK * DMODEL;      // 4096*512

    pack_kernel<<<1280, 256, 0, stream>>>(xv, xt, wq, wk, wv, wo,
                                          xvb, xtb, wqb, wkb, wvb, wob);
    gemmQKV<<<dim3(96, 8), 256, 0, stream>>>(xvb, xtb, wqb, wkb, wvb, qb, kbm, vbt);
    attn_kernel<<<512, 512, 0, stream>>>(qb, kbm, vbt, yb);
    gemmOut<<<dim3(64, 8), 256, 0, stream>>>(yb, wob, (float*)d_out);
}

// Round 14
// 52.258 us; speedup vs baseline: 1.1242x; 1.0285x over previous
//
#include <hip/hip_runtime.h>
#include <hip/hip_bf16.h>
#include <math.h>

#define N_TOK 4096
#define M_TOK 1024
#define DMODEL 512
#define NHEAD 8
#define DHEAD 64

typedef __attribute__((ext_vector_type(8))) short short8;
typedef __attribute__((ext_vector_type(4))) float f32x4;
typedef __attribute__((ext_vector_type(4))) float float4v;

static __device__ __forceinline__ short f2bf(float f) {
    union { float f; unsigned u; } v; v.f = f;
    unsigned r = v.u + 0x7fffu + ((v.u >> 16) & 1u);
    return (short)(r >> 16);
}

// ---------------------------------------------------------------------------
// Pack v2 (r11-proven). Blocks [0,192): wq/wk/wv head-tile transposes via
// LDS. Blocks [192,256): wo. Blocks [256+): xv/xt bf16 conversion.
// ---------------------------------------------------------------------------
__global__ __launch_bounds__(256) void pack_kernel(
        const float* __restrict__ xv, const float* __restrict__ xt,
        const float* __restrict__ wq, const float* __restrict__ wk,
        const float* __restrict__ wv, const float* __restrict__ wo,
        short* __restrict__ xvb, short* __restrict__ xtb,
        short* __restrict__ wqb, short* __restrict__ wkb,
        short* __restrict__ wvb, short* __restrict__ wob) {
    int bid = blockIdx.x;
    int t = threadIdx.x;
    if (bid < 256) {
        __shared__ float lds[64][65];
        const float* src;
        short* dst;
        int srstride;
        int dr0, dc0;
        if (bid < 192) {
            int mat = bid >> 6;
            int hb = bid & 63;
            int h = hb >> 3, dt = hb & 7;
            const float* W = (mat == 0) ? wq : (mat == 1) ? wk : wv;
            src = W + (size_t)h * (DMODEL * DHEAD) + (size_t)(dt * 64) * DHEAD;
            srstride = DHEAD;
            dst = (mat == 0) ? wqb : (mat == 1) ? wkb : wvb;
            dr0 = h * 64;
            dc0 = dt * 64;
        } else {
            int b = bid - 192;
            int rt = b >> 3, ct = b & 7;
            src = wo + (size_t)(rt * 64) * DMODEL + ct * 64;
            srstride = DMODEL;
            dst = wob;
            dr0 = ct * 64;
            dc0 = rt * 64;
        }
        {
            int r = t >> 2, c0 = (t & 3) * 16;
            const float* s = src + (size_t)r * srstride + c0;
            #pragma unroll
            for (int j = 0; j < 4; j++) {
                float4v v = *(const float4v*)(s + j * 4);
                lds[r][c0 + j * 4 + 0] = v[0];
                lds[r][c0 + j * 4 + 1] = v[1];
                lds[r][c0 + j * 4 + 2] = v[2];
                lds[r][c0 + j * 4 + 3] = v[3];
            }
        }
        __syncthreads();
        {
            int outr = t >> 2, c0 = (t & 3) * 16;
            short8 o0, o1;
            #pragma unroll
            for (int j = 0; j < 8; j++) {
                o0[j] = f2bf(lds[c0 + j][outr]);
                o1[j] = f2bf(lds[c0 + 8 + j][outr]);
            }
            short* d = dst + (size_t)(dr0 + outr) * DMODEL + dc0 + c0;
            *(short8*)d = o0;
            *(short8*)(d + 8) = o1;
        }
        return;
    }
    int idx = (bid - 256) * 256 + t;
    int stride = (gridDim.x - 256) * 256;
    const int CXV = N_TOK * DMODEL / 8;
    const int CXT = M_TOK * DMODEL / 8;
    for (int c = idx; c < CXV; c += stride) {
        float4v f0 = *(const float4v*)&xv[c * 8];
        float4v f1 = *(const float4v*)&xv[c * 8 + 4];
        short8 o;
        #pragma unroll
        for (int j = 0; j < 4; j++) { o[j] = f2bf(f0[j]); o[j + 4] = f2bf(f1[j]); }
        *(short8*)&xvb[c * 8] = o;
    }
    for (int c = idx; c < CXT; c += stride) {
        float4v f0 = *(const float4v*)&xt[c * 8];
        float4v f1 = *(const float4v*)&xt[c * 8 + 4];
        short8 o;
        #pragma unroll
        for (int j = 0; j < 4; j++) { o[j] = f2bf(f0[j]); o[j + 4] = f2bf(f1[j]); }
        *(short8*)&xtb[c * 8] = o;
    }
}

// ---------------------------------------------------------------------------
// GEMM body v4: 64x64 tile, BK=64, 8 WAVES (512 threads) — wave w owns a
// 16x32 quadrant (1x2 frags). Same reg-staging + prefetch-after-barrier as
// the r8-proven body, but 2x waves/CU for latency hiding (the r13 attn win
// mechanism). Staging: 1 short8 per thread per tensor.
// ---------------------------------------------------------------------------
template<typename EPI>
static __device__ __forceinline__ void gemm_body8(const short* __restrict__ A,
                                                  const short* __restrict__ BT,
                                                  int m0, int n0, EPI epi) {
    __shared__ __align__(16) short As[64][72];
    __shared__ __align__(16) short Bs[64][72];
    int t = threadIdx.x;
    int lane = t & 63, w = t >> 6;
    int wr = w & 3, wc = w >> 2;          // rows wr*16, cols wc*32
    int l15 = lane & 15, g = lane >> 4;

    int row = t >> 3, c0 = (t & 7) * 8;
    const short* gA = A + (size_t)(m0 + row) * DMODEL + c0;
    const short* gB = BT + (size_t)(n0 + row) * DMODEL + c0;

    short8 ra = *(const short8*)gA;
    short8 rb = *(const short8*)gB;

    f32x4 acc[2] = {};
    #pragma unroll
    for (int step = 0; step < DMODEL / 64; ++step) {
        *(short8*)&As[row][c0] = ra;
        *(short8*)&Bs[row][c0] = rb;
        __syncthreads();
        if (step < DMODEL / 64 - 1) {      // issue next-step loads early
            gA += 64; gB += 64;
            ra = *(const short8*)gA;
            rb = *(const short8*)gB;
        }
        #pragma unroll
        for (int ks = 0; ks < 2; ks++) {
            short8 a = *(short8*)&As[wr * 16 + l15][ks * 32 + g * 8];
            #pragma unroll
            for (int fc = 0; fc < 2; fc++) {
                short8 b = *(short8*)&Bs[wc * 32 + fc * 16 + l15][ks * 32 + g * 8];
                acc[fc] = __builtin_amdgcn_mfma_f32_16x16x32_bf16(a, b, acc[fc], 0, 0, 0);
            }
        }
        __syncthreads();
    }
    #pragma unroll
    for (int fc = 0; fc < 2; fc++)
        #pragma unroll
        for (int r = 0; r < 4; r++) {
            int orow = m0 + wr * 16 + g * 4 + r;
            int ocol = n0 + wc * 32 + fc * 16 + l15;
            epi(orow, ocol, acc[fc][r]);
        }
}

// ---------------------------------------------------------------------------
// Q, K, V projections in ONE launch. Flat 768 blocks x 512 threads (3/CU):
//   bx<512: Q;  bx<640: K;  else: V (transposed out V^T[d][1024])
// ---------------------------------------------------------------------------
__global__ __launch_bounds__(512) void gemmQKV(const short* __restrict__ xvb,
                                               const short* __restrict__ xtb,
                                               const short* __restrict__ wqb,
                                               const short* __restrict__ wkb,
                                               const short* __restrict__ wvb,
                                               short* __restrict__ qb,
                                               short* __restrict__ kbm,
                                               short* __restrict__ vbt) {
    int bx = blockIdx.x;
    if (bx < 512) {
        short* C = qb;
        gemm_body8(xvb, wqb, (bx >> 3) * 64, (bx & 7) * 64,
                   [&](int row, int col, float v) { C[(size_t)row * DMODEL + col] = f2bf(v); });
    } else if (bx < 640) {
        int b = bx - 512;
        short* C = kbm;
        gemm_body8(xtb, wkb, (b >> 3) * 64, (b & 7) * 64,
                   [&](int row, int col, float v) { C[(size_t)row * DMODEL + col] = f2bf(v); });
    } else {
        int b = bx - 640;
        short* C = vbt;
        gemm_body8(xtb, wvb, (b >> 3) * 64, (b & 7) * 64,
                   [&](int row, int col, float v) { C[(size_t)col * M_TOK + row] = f2bf(v); });
    }
}

// ---------------------------------------------------------------------------
// Final GEMM: out = Y * Wout(^T stored) + PE. 512 blocks x 512 threads.
// ---------------------------------------------------------------------------
__global__ __launch_bounds__(512) void gemmOut(const short* __restrict__ A,
                                               const short* __restrict__ BT,
                                               float* __restrict__ Cout) {
    __shared__ float ifreq[256];
    if (threadIdx.x < 256)
        ifreq[threadIdx.x] = __expf(-(float)threadIdx.x * (9.210340371976184f / 512.0f));
    __syncthreads();
    gemm_body8(A, BT, blockIdx.x * 64, blockIdx.y * 64,
               [&](int row, int col, float v) {
                   float x = (float)row * ifreq[col >> 1];
                   float s, c;
                   __sincosf(x, &s, &c);
                   Cout[(size_t)row * DMODEL + col] = v + ((col & 1) ? c : s);
               });
}

// ---------------------------------------------------------------------------
// Attention v7 (r13-proven, unchanged): 512 threads = 8 waves = 4 q-subtiles
// x 2 key-halves; reg-staged K/V; single-pass exp2 softmax; LDS-overlay merge.
// ---------------------------------------------------------------------------
struct AttnS {
    short Ks[2][64][72];
    short Vt[2][64][72];
    short Ps[8][16][72];
};
struct MergeS {
    f32x4 macc[4][4][64];
    f32x4 mrs[4][64];
};
union AttnU { AttnS a; MergeS m; };

__global__ __launch_bounds__(512) void attn_kernel(const short* __restrict__ Qb,
                                                   const short* __restrict__ Kb,
                                                   const short* __restrict__ VbT,
                                                   short* __restrict__ Yb) {
    __shared__ __align__(16) AttnU u;

    int bid = blockIdx.x;
    int h = bid & 7;
    int n0 = (bid >> 3) * 64;
    int t = threadIdx.x;
    int lane = t & 63, w = t >> 6;
    int qg = w & 3, kh = w >> 2;
    int l15 = lane & 15, g = lane >> 4;

    int sh = t >> 8;
    int tt = t & 255;
    int row = tt >> 2, c0 = (tt & 3) * 16;
    const short* gK = Kb + (size_t)(sh * 512 + row) * DMODEL + h * DHEAD + c0;
    const short* gV = VbT + (size_t)(h * DHEAD + row) * M_TOK + sh * 512 + c0;

    short8 k0 = *(const short8*)gK;
    short8 k1 = *(const short8*)(gK + 8);
    short8 v0 = *(const short8*)gV;
    short8 v1 = *(const short8*)(gV + 8);

    const short* qrow = Qb + (size_t)(n0 + qg * 16 + l15) * DMODEL + h * DHEAD;
    short8 qa0 = *(const short8*)(qrow + g * 8);
    short8 qa1 = *(const short8*)(qrow + 32 + g * 8);

    f32x4 acc[4] = {};
    f32x4 rsum = {};

    for (int it = 0; it < 8; ++it) {
        *(short8*)&u.a.Ks[sh][row][c0]     = k0;
        *(short8*)&u.a.Ks[sh][row][c0 + 8] = k1;
        *(short8*)&u.a.Vt[sh][row][c0]     = v0;
        *(short8*)&u.a.Vt[sh][row][c0 + 8] = v1;
        __syncthreads();
        if (it < 7) {
            gK += (size_t)64 * DMODEL;
            gV += 64;
            k0 = *(const short8*)gK;
            k1 = *(const short8*)(gK + 8);
            v0 = *(const short8*)gV;
            v1 = *(const short8*)(gV + 8);
        }
        #pragma unroll
        for (int kt = 0; kt < 4; kt++) {
            short8 kf0 = *(short8*)&u.a.Ks[kh][kt * 16 + l15][g * 8];
            short8 kf1 = *(short8*)&u.a.Ks[kh][kt * 16 + l15][32 + g * 8];
            f32x4 e = {};
            e = __builtin_amdgcn_mfma_f32_16x16x32_bf16(qa0, kf0, e, 0, 0, 0);
            e = __builtin_amdgcn_mfma_f32_16x16x32_bf16(qa1, kf1, e, 0, 0, 0);
            #pragma unroll
            for (int r = 0; r < 4; r++) {
                float p = exp2f(e[r] * 1.44269504f);
                rsum[r] += p;
                u.a.Ps[w][g * 4 + r][kt * 16 + l15] = f2bf(p);
            }
        }
        #pragma unroll
        for (int kb2 = 0; kb2 < 2; kb2++) {
            short8 pa = *(short8*)&u.a.Ps[w][l15][kb2 * 32 + g * 8];
            #pragma unroll
            for (int nt = 0; nt < 4; nt++) {
                short8 vf = *(short8*)&u.a.Vt[kh][nt * 16 + l15][kb2 * 32 + g * 8];
                acc[nt] = __builtin_amdgcn_mfma_f32_16x16x32_bf16(pa, vf, acc[nt], 0, 0, 0);
            }
        }
        __syncthreads();
    }

    if (kh == 1) {
        #pragma unroll
        for (int nt = 0; nt < 4; nt++) u.m.macc[qg][nt][lane] = acc[nt];
        u.m.mrs[qg][lane] = rsum;
    }
    __syncthreads();
    if (kh == 0) {
        #pragma unroll
        for (int nt = 0; nt < 4; nt++) acc[nt] += u.m.macc[qg][nt][lane];
        rsum += u.m.mrs[qg][lane];
        #pragma unroll
        for (int r = 0; r < 4; r++) {
            float s = rsum[r];
            s += __shfl_xor(s, 1);
            s += __shfl_xor(s, 2);
            s += __shfl_xor(s, 4);
            s += __shfl_xor(s, 8);
            rsum[r] = s;
        }
        #pragma unroll
        for (int nt = 0; nt < 4; nt++)
            #pragma unroll
            for (int r = 0; r < 4; r++) {
                float y = acc[nt][r] / rsum[r];
                Yb[(size_t)(n0 + qg * 16 + g * 4 + r) * DMODEL + h * DHEAD + nt * 16 + l15] = f2bf(y);
            }
    }
}

// ---------------------------------------------------------------------------
extern "C" void kernel_launch(void* const* d_in, const int* in_sizes, int n_in,
                              void* d_out, int out_size, void* d_ws, size_t ws_size,
                              hipStream_t stream) {
    const float* xv = (const float*)d_in[0];
    const float* xt = (const float*)d_in[1];
    const float* wq = (const float*)d_in[2];
    const float* wk = (const float*)d_in[3];
    const float* wv = (const float*)d_in[4];
    const float* wo = (const float*)d_in[5];

    short* xvb = (short*)d_ws;              // 4096*512
    short* xtb = xvb + N_TOK * DMODEL;      // 1024*512
    short* wqb = xtb + M_TOK * DMODEL;      // 512*512 (B^T)
    short* wkb = wqb + DMODEL * DMODEL;
    short* wvb = wkb + DMODEL * DMODEL;
    short* wob = wvb + DMODEL * DMODEL;
    short* qb  = wob + DMODEL * DMODEL;     // 4096*512
    short* kbm = qb  + N_TOK * DMODEL;      // 1024*512
    short* vbt = kbm + M_TOK * DMODEL;      // 512*1024 (V^T)
    short* yb  = vbt + M_TOK * DMODEL;      // 4096*512

    pack_kernel<<<1280, 256, 0, stream>>>(xv, xt, wq, wk, wv, wo,
                                          xvb, xtb, wqb, wkb, wvb, wob);
    gemmQKV<<<768, 512, 0, stream>>>(xvb, xtb, wqb, wkb, wvb, qb, kbm, vbt);
    attn_kernel<<<512, 512, 0, stream>>>(qb, kbm, vbt, yb);
    gemmOut<<<dim3(64, 8), 512, 0, stream>>>(yb, wob, (float*)d_out);
}

// Round 15
// 50.984 us; speedup vs baseline: 1.1523x; 1.0250x over previous
//
#include <hip/hip_runtime.h>
#include <hip/hip_bf16.h>
#include <math.h>

#define N_TOK 4096
#define M_TOK 1024
#define DMODEL 512
#define NHEAD 8
#define DHEAD 64
#define LOG2E 1.44269504f

typedef __attribute__((ext_vector_type(8))) short short8;
typedef __attribute__((ext_vector_type(4))) float f32x4;
typedef __attribute__((ext_vector_type(4))) float float4v;

static __device__ __forceinline__ short f2bf(float f) {
    union { float f; unsigned u; } v; v.f = f;
    unsigned r = v.u + 0x7fffu + ((v.u >> 16) & 1u);
    return (short)(r >> 16);
}

// ---------------------------------------------------------------------------
// Pack v2 (r11-proven). Blocks [0,192): wq/wk/wv head-tile transposes via
// LDS. Blocks [192,256): wo. Blocks [256+): xv/xt bf16 conversion.
// ---------------------------------------------------------------------------
__global__ __launch_bounds__(256) void pack_kernel(
        const float* __restrict__ xv, const float* __restrict__ xt,
        const float* __restrict__ wq, const float* __restrict__ wk,
        const float* __restrict__ wv, const float* __restrict__ wo,
        short* __restrict__ xvb, short* __restrict__ xtb,
        short* __restrict__ wqb, short* __restrict__ wkb,
        short* __restrict__ wvb, short* __restrict__ wob) {
    int bid = blockIdx.x;
    int t = threadIdx.x;
    if (bid < 256) {
        __shared__ float lds[64][65];
        const float* src;
        short* dst;
        int srstride;
        int dr0, dc0;
        if (bid < 192) {
            int mat = bid >> 6;
            int hb = bid & 63;
            int h = hb >> 3, dt = hb & 7;
            const float* W = (mat == 0) ? wq : (mat == 1) ? wk : wv;
            src = W + (size_t)h * (DMODEL * DHEAD) + (size_t)(dt * 64) * DHEAD;
            srstride = DHEAD;
            dst = (mat == 0) ? wqb : (mat == 1) ? wkb : wvb;
            dr0 = h * 64;
            dc0 = dt * 64;
        } else {
            int b = bid - 192;
            int rt = b >> 3, ct = b & 7;
            src = wo + (size_t)(rt * 64) * DMODEL + ct * 64;
            srstride = DMODEL;
            dst = wob;
            dr0 = ct * 64;
            dc0 = rt * 64;
        }
        {
            int r = t >> 2, c0 = (t & 3) * 16;
            const float* s = src + (size_t)r * srstride + c0;
            #pragma unroll
            for (int j = 0; j < 4; j++) {
                float4v v = *(const float4v*)(s + j * 4);
                lds[r][c0 + j * 4 + 0] = v[0];
                lds[r][c0 + j * 4 + 1] = v[1];
                lds[r][c0 + j * 4 + 2] = v[2];
                lds[r][c0 + j * 4 + 3] = v[3];
            }
        }
        __syncthreads();
        {
            int outr = t >> 2, c0 = (t & 3) * 16;
            short8 o0, o1;
            #pragma unroll
            for (int j = 0; j < 8; j++) {
                o0[j] = f2bf(lds[c0 + j][outr]);
                o1[j] = f2bf(lds[c0 + 8 + j][outr]);
            }
            short* d = dst + (size_t)(dr0 + outr) * DMODEL + dc0 + c0;
            *(short8*)d = o0;
            *(short8*)(d + 8) = o1;
        }
        return;
    }
    int idx = (bid - 256) * 256 + t;
    int stride = (gridDim.x - 256) * 256;
    const int CXV = N_TOK * DMODEL / 8;
    const int CXT = M_TOK * DMODEL / 8;
    for (int c = idx; c < CXV; c += stride) {
        float4v f0 = *(const float4v*)&xv[c * 8];
        float4v f1 = *(const float4v*)&xv[c * 8 + 4];
        short8 o;
        #pragma unroll
        for (int j = 0; j < 4; j++) { o[j] = f2bf(f0[j]); o[j + 4] = f2bf(f1[j]); }
        *(short8*)&xvb[c * 8] = o;
    }
    for (int c = idx; c < CXT; c += stride) {
        float4v f0 = *(const float4v*)&xt[c * 8];
        float4v f1 = *(const float4v*)&xt[c * 8 + 4];
        short8 o;
        #pragma unroll
        for (int j = 0; j < 4; j++) { o[j] = f2bf(f0[j]); o[j + 4] = f2bf(f1[j]); }
        *(short8*)&xtb[c * 8] = o;
    }
}

// ---------------------------------------------------------------------------
// GEMM body v4 (r14-proven): 64x64 tile, BK=64, 8 waves (512 threads), wave
// w owns 16x32 (1x2 frags). Reg-staging + prefetch-after-barrier.
// ---------------------------------------------------------------------------
template<typename EPI>
static __device__ __forceinline__ void gemm_body8(const short* __restrict__ A,
                                                  const short* __restrict__ BT,
                                                  int m0, int n0, EPI epi) {
    __shared__ __align__(16) short As[64][72];
    __shared__ __align__(16) short Bs[64][72];
    int t = threadIdx.x;
    int lane = t & 63, w = t >> 6;
    int wr = w & 3, wc = w >> 2;
    int l15 = lane & 15, g = lane >> 4;

    int row = t >> 3, c0 = (t & 7) * 8;
    const short* gA = A + (size_t)(m0 + row) * DMODEL + c0;
    const short* gB = BT + (size_t)(n0 + row) * DMODEL + c0;

    short8 ra = *(const short8*)gA;
    short8 rb = *(const short8*)gB;

    f32x4 acc[2] = {};
    #pragma unroll
    for (int step = 0; step < DMODEL / 64; ++step) {
        *(short8*)&As[row][c0] = ra;
        *(short8*)&Bs[row][c0] = rb;
        __syncthreads();
        if (step < DMODEL / 64 - 1) {
            gA += 64; gB += 64;
            ra = *(const short8*)gA;
            rb = *(const short8*)gB;
        }
        #pragma unroll
        for (int ks = 0; ks < 2; ks++) {
            short8 a = *(short8*)&As[wr * 16 + l15][ks * 32 + g * 8];
            #pragma unroll
            for (int fc = 0; fc < 2; fc++) {
                short8 b = *(short8*)&Bs[wc * 32 + fc * 16 + l15][ks * 32 + g * 8];
                acc[fc] = __builtin_amdgcn_mfma_f32_16x16x32_bf16(a, b, acc[fc], 0, 0, 0);
            }
        }
        __syncthreads();
    }
    #pragma unroll
    for (int fc = 0; fc < 2; fc++)
        #pragma unroll
        for (int r = 0; r < 4; r++) {
            int orow = m0 + wr * 16 + g * 4 + r;
            int ocol = n0 + wc * 32 + fc * 16 + l15;
            epi(orow, ocol, acc[fc][r]);
        }
}

// ---------------------------------------------------------------------------
// K, V projections (Q is fused into attn). 256 blocks x 512 threads:
//   bx<128: K row-major, scaled by LOG2E (folds softmax base conversion);
//   else:   V transposed out V^T[d][1024].
// ---------------------------------------------------------------------------
__global__ __launch_bounds__(512) void gemmKV(const short* __restrict__ xtb,
                                              const short* __restrict__ wkb,
                                              const short* __restrict__ wvb,
                                              short* __restrict__ kbm,
                                              short* __restrict__ vbt) {
    int bx = blockIdx.x;
    if (bx < 128) {
        gemm_body8(xtb, wkb, (bx >> 3) * 64, (bx & 7) * 64,
                   [&](int row, int col, float v) { kbm[(size_t)row * DMODEL + col] = f2bf(v * LOG2E); });
    } else {
        int b = bx - 128;
        gemm_body8(xtb, wvb, (b >> 3) * 64, (b & 7) * 64,
                   [&](int row, int col, float v) { vbt[(size_t)col * M_TOK + row] = f2bf(v); });
    }
}

// ---------------------------------------------------------------------------
// Final GEMM: out = Y * Wout(^T stored) + PE. (64,8) x 512 threads.
// ---------------------------------------------------------------------------
__global__ __launch_bounds__(512) void gemmOut(const short* __restrict__ A,
                                               const short* __restrict__ BT,
                                               float* __restrict__ Cout) {
    __shared__ float ifreq[256];
    if (threadIdx.x < 256)
        ifreq[threadIdx.x] = __expf(-(float)threadIdx.x * (9.210340371976184f / 512.0f));
    __syncthreads();
    gemm_body8(A, BT, blockIdx.x * 64, blockIdx.y * 64,
               [&](int row, int col, float v) {
                   float x = (float)row * ifreq[col >> 1];
                   float s, c;
                   __sincosf(x, &s, &c);
                   Cout[(size_t)row * DMODEL + col] = v + ((col & 1) ? c : s);
               });
}

// ---------------------------------------------------------------------------
// Attention v8: v7 + FUSED Q-projection prologue. Block = 64 q x 1 head,
// 8 waves. Prologue: Q-tile GEMM (xv[n0..n0+63] @ Wq_h) -> Qs LDS (staging
// through union-overlaid As/Bs). Main loop: v7 (4 q-subtiles x 2 key-halves,
// reg-staged K/V, exp2 softmax with LOG2E pre-folded into K, LDS merge).
// ---------------------------------------------------------------------------
struct AttnS {
    short Ks[2][64][72];
    short Vt[2][64][72];
    short Ps[8][16][72];
};
struct MergeS {
    f32x4 macc[4][4][64];
    f32x4 mrs[4][64];
};
struct GemmS {
    short As[64][72];
    short Bs[64][72];
};
union AttnU { AttnS a; MergeS m; GemmS g; };

__global__ __launch_bounds__(512) void attn_kernel(const short* __restrict__ xvb,
                                                   const short* __restrict__ wqb,
                                                   const short* __restrict__ Kb,
                                                   const short* __restrict__ VbT,
                                                   short* __restrict__ Yb) {
    __shared__ __align__(16) AttnU u;
    __shared__ __align__(16) short Qs[64][72];

    int bid = blockIdx.x;
    int h = bid & 7;
    int n0 = (bid >> 3) * 64;
    int t = threadIdx.x;
    int lane = t & 63, w = t >> 6;
    int qg = w & 3, kh = w >> 2;
    int l15 = lane & 15, g = lane >> 4;

    // ---- Q-projection prologue (gemm_body8 pattern into Qs) ----
    {
        int row = t >> 3, c0 = (t & 7) * 8;
        const short* gA = xvb + (size_t)(n0 + row) * DMODEL + c0;
        const short* gB = wqb + (size_t)(h * DHEAD + row) * DMODEL + c0;
        short8 ra = *(const short8*)gA;
        short8 rb = *(const short8*)gB;
        int wr = w & 3, wc = w >> 2;
        f32x4 qacc[2] = {};
        #pragma unroll
        for (int step = 0; step < DMODEL / 64; ++step) {
            *(short8*)&u.g.As[row][c0] = ra;
            *(short8*)&u.g.Bs[row][c0] = rb;
            __syncthreads();
            if (step < DMODEL / 64 - 1) {
                gA += 64; gB += 64;
                ra = *(const short8*)gA;
                rb = *(const short8*)gB;
            }
            #pragma unroll
            for (int ks = 0; ks < 2; ks++) {
                short8 a = *(short8*)&u.g.As[wr * 16 + l15][ks * 32 + g * 8];
                #pragma unroll
                for (int fc = 0; fc < 2; fc++) {
                    short8 b = *(short8*)&u.g.Bs[wc * 32 + fc * 16 + l15][ks * 32 + g * 8];
                    qacc[fc] = __builtin_amdgcn_mfma_f32_16x16x32_bf16(a, b, qacc[fc], 0, 0, 0);
                }
            }
            __syncthreads();
        }
        #pragma unroll
        for (int fc = 0; fc < 2; fc++)
            #pragma unroll
            for (int r = 0; r < 4; r++)
                Qs[wr * 16 + g * 4 + r][wc * 32 + fc * 16 + l15] = f2bf(qacc[fc][r]);
        __syncthreads();
    }

    short8 qa0 = *(short8*)&Qs[qg * 16 + l15][g * 8];
    short8 qa1 = *(short8*)&Qs[qg * 16 + l15][32 + g * 8];

    // ---- K/V staging pointers ----
    int sh = t >> 8;
    int tt = t & 255;
    int row = tt >> 2, c0 = (tt & 3) * 16;
    const short* gK = Kb + (size_t)(sh * 512 + row) * DMODEL + h * DHEAD + c0;
    const short* gV = VbT + (size_t)(h * DHEAD + row) * M_TOK + sh * 512 + c0;

    short8 k0 = *(const short8*)gK;
    short8 k1 = *(const short8*)(gK + 8);
    short8 v0 = *(const short8*)gV;
    short8 v1 = *(const short8*)(gV + 8);

    f32x4 acc[4] = {};
    f32x4 rsum = {};

    for (int it = 0; it < 8; ++it) {
        *(short8*)&u.a.Ks[sh][row][c0]     = k0;
        *(short8*)&u.a.Ks[sh][row][c0 + 8] = k1;
        *(short8*)&u.a.Vt[sh][row][c0]     = v0;
        *(short8*)&u.a.Vt[sh][row][c0 + 8] = v1;
        __syncthreads();
        if (it < 7) {
            gK += (size_t)64 * DMODEL;
            gV += 64;
            k0 = *(const short8*)gK;
            k1 = *(const short8*)(gK + 8);
            v0 = *(const short8*)gV;
            v1 = *(const short8*)(gV + 8);
        }
        #pragma unroll
        for (int kt = 0; kt < 4; kt++) {
            short8 kf0 = *(short8*)&u.a.Ks[kh][kt * 16 + l15][g * 8];
            short8 kf1 = *(short8*)&u.a.Ks[kh][kt * 16 + l15][32 + g * 8];
            f32x4 e = {};
            e = __builtin_amdgcn_mfma_f32_16x16x32_bf16(qa0, kf0, e, 0, 0, 0);
            e = __builtin_amdgcn_mfma_f32_16x16x32_bf16(qa1, kf1, e, 0, 0, 0);
            #pragma unroll
            for (int r = 0; r < 4; r++) {
                float p = exp2f(e[r]);           // LOG2E folded into K
                rsum[r] += p;
                u.a.Ps[w][g * 4 + r][kt * 16 + l15] = f2bf(p);
            }
        }
        #pragma unroll
        for (int kb2 = 0; kb2 < 2; kb2++) {
            short8 pa = *(short8*)&u.a.Ps[w][l15][kb2 * 32 + g * 8];
            #pragma unroll
            for (int nt = 0; nt < 4; nt++) {
                short8 vf = *(short8*)&u.a.Vt[kh][nt * 16 + l15][kb2 * 32 + g * 8];
                acc[nt] = __builtin_amdgcn_mfma_f32_16x16x32_bf16(pa, vf, acc[nt], 0, 0, 0);
            }
        }
        __syncthreads();
    }

    if (kh == 1) {
        #pragma unroll
        for (int nt = 0; nt < 4; nt++) u.m.macc[qg][nt][lane] = acc[nt];
        u.m.mrs[qg][lane] = rsum;
    }
    __syncthreads();
    if (kh == 0) {
        #pragma unroll
        for (int nt = 0; nt < 4; nt++) acc[nt] += u.m.macc[qg][nt][lane];
        rsum += u.m.mrs[qg][lane];
        #pragma unroll
        for (int r = 0; r < 4; r++) {
            float s = rsum[r];
            s += __shfl_xor(s, 1);
            s += __shfl_xor(s, 2);
            s += __shfl_xor(s, 4);
            s += __shfl_xor(s, 8);
            rsum[r] = s;
        }
        #pragma unroll
        for (int nt = 0; nt < 4; nt++)
            #pragma unroll
            for (int r = 0; r < 4; r++) {
                float y = acc[nt][r] / rsum[r];
                Yb[(size_t)(n0 + qg * 16 + g * 4 + r) * DMODEL + h * DHEAD + nt * 16 + l15] = f2bf(y);
            }
    }
}

// ---------------------------------------------------------------------------
extern "C" void kernel_launch(void* const* d_in, const int* in_sizes, int n_in,
                              void* d_out, int out_size, void* d_ws, size_t ws_size,
                              hipStream_t stream) {
    const float* xv = (const float*)d_in[0];
    const float* xt = (const float*)d_in[1];
    const float* wq = (const float*)d_in[2];
    const float* wk = (const float*)d_in[3];
    const float* wv = (const float*)d_in[4];
    const float* wo = (const float*)d_in[5];

    short* xvb = (short*)d_ws;              // 4096*512
    short* xtb = xvb + N_TOK * DMODEL;      // 1024*512
    short* wqb = xtb + M_TOK * DMODEL;      // 512*512 (B^T)
    short* wkb = wqb + DMODEL * DMODEL;
    short* wvb = wkb + DMODEL * DMODEL;
    short* wob = wvb + DMODEL * DMODEL;
    short* kbm = wob + DMODEL * DMODEL;     // 1024*512 (pre-scaled by LOG2E)
    short* vbt = kbm + M_TOK * DMODEL;      // 512*1024 (V^T)
    short* yb  = vbt + M_TOK * DMODEL;      // 4096*512

    pack_kernel<<<1280, 256, 0, stream>>>(xv, xt, wq, wk, wv, wo,
                                          xvb, xtb, wqb, wkb, wvb, wob);
    gemmKV<<<256, 512, 0, stream>>>(xtb, wkb, wvb, kbm, vbt);
    attn_kernel<<<512, 512, 0, stream>>>(xvb, wqb, kbm, vbt, yb);
    gemmOut<<<dim3(64, 8), 512, 0, stream>>>(yb, wob, (float*)d_out);
}